// Round 3
// baseline (282.578 us; speedup 1.0000x reference)
//
#include <hip/hip_runtime.h>

#define TT 200
#define FF 32
#define HH 50
#define HP 52   // hidden padded to multiple of 4 for float4 LDS reads

__device__ __forceinline__ float rl(float v, int srclane) {
    return __int_as_float(__builtin_amdgcn_readlane(__float_as_int(v), srclane));
}

// tanh(x) = 1 - 2/(exp(2x)+1); ~1e-6 rel, saturates correctly for large |x|.
__device__ __forceinline__ float fast_tanh(float x) {
    float e = __expf(2.0f * x);
    return 1.0f - __fdividef(2.0f, e + 1.0f);
}

// One wave per batch row. Lane j<50 owns h[j] and W[:,j], U[:,j] in VGPRs.
// amdgpu_waves_per_eu(1,4): min=1 gives regalloc a 512-VGPR budget so the 84
// weight values actually stay resident (launch_bounds(256,4) still spilled
// them to scratch: VGPR=64, WRITE_SIZE=6MB in round 2). ~110 VGPRs still
// fits the 4 waves/SIMD our 4096-wave grid supplies.
// h broadcast: 1 ds_write + 13 uniform float4 LDS reads (LDS pipe, parallel
// to VALU). x broadcast: readlane. 4 accumulators break the FMA dep chain.
__global__
__attribute__((amdgpu_flat_work_group_size(256, 256)))
__attribute__((amdgpu_waves_per_eu(1, 4)))
void rnn_fused(
    const float* __restrict__ x, const float* __restrict__ W,
    const float* __restrict__ U, const float* __restrict__ b,
    const float* __restrict__ Wd, const float* __restrict__ bd,
    float* __restrict__ out, int B)
{
    __shared__ float sh[4][HP];
    const int lane = threadIdx.x & 63;
    const int wid  = threadIdx.x >> 6;
    const int row  = blockIdx.x * 4 + wid;
    if (row >= B) return;
    const int j = (lane < HH) ? lane : 0;   // clamp for safe loads

    float w[FF];
#pragma unroll
    for (int f = 0; f < FF; ++f) w[f] = W[f * HH + j];
    float u[HP];
#pragma unroll
    for (int k = 0; k < HH; ++k) u[k] = U[k * HH + j];
    u[HH] = 0.0f; u[HH + 1] = 0.0f;         // pad columns multiply to zero
    const float bj = b[j];

    float* shw = sh[wid];                   // per-wave region: no syncthreads needed
    if (lane < HP) shw[lane] = 0.0f;        // h0 = 0 (incl. pad slots)

    const float* xr = x + (size_t)row * (TT * FF);
    float h  = 0.0f;
    float xv = (lane < FF) ? xr[lane] : 0.0f;

    for (int t = 0; t < TT; ++t) {
        // prefetch next timestep's x (clamped re-read on last step: harmless)
        const int tn = (t + 1 < TT) ? (t + 1) : (TT - 1);
        const float xn = (lane < FF) ? xr[tn * FF + lane] : 0.0f;

        float a0 = bj, a1 = 0.0f, a2 = 0.0f, a3 = 0.0f;

        // x part: readlane broadcast (VALU) — issued first to give the
        // ds_write->ds_read dependency time to drain.
#pragma unroll
        for (int f = 0; f < FF; f += 4) {
            a0 = fmaf(rl(xv, f + 0), w[f + 0], a0);
            a1 = fmaf(rl(xv, f + 1), w[f + 1], a1);
            a2 = fmaf(rl(xv, f + 2), w[f + 2], a2);
            a3 = fmaf(rl(xv, f + 3), w[f + 3], a3);
        }
        // h part: uniform-address float4 LDS broadcast (conflict-free)
#pragma unroll
        for (int q = 0; q < HP / 4; ++q) {
            const float4 hb = ((const float4*)shw)[q];
            a0 = fmaf(hb.x, u[4 * q + 0], a0);
            a1 = fmaf(hb.y, u[4 * q + 1], a1);
            a2 = fmaf(hb.z, u[4 * q + 2], a2);
            a3 = fmaf(hb.w, u[4 * q + 3], a3);
        }

        h = fast_tanh((a0 + a1) + (a2 + a3));
        if (lane < HH) shw[lane] = h;       // publish h_t for next step
        xv = xn;
    }

    // head: out[row] = relu(sum_j h[j]*Wd[j] + bd)
    float p = (lane < HH) ? h * Wd[j] : 0.0f;
#pragma unroll
    for (int m = 32; m >= 1; m >>= 1) p += __shfl_xor(p, m);
    if (lane == 0) out[row] = fmaxf(p + bd[0], 0.0f);
}

extern "C" void kernel_launch(void* const* d_in, const int* in_sizes, int n_in,
                              void* d_out, int out_size, void* d_ws, size_t ws_size,
                              hipStream_t stream) {
    const float* x  = (const float*)d_in[0];
    const float* W  = (const float*)d_in[1];
    const float* U  = (const float*)d_in[2];
    const float* b  = (const float*)d_in[3];
    const float* Wd = (const float*)d_in[4];
    const float* bd = (const float*)d_in[5];
    float* out = (float*)d_out;
    const int B = out_size;                 // 4096 rows
    dim3 grid((B + 3) / 4), block(256);     // 1 row per wave, 4 waves per block
    hipLaunchKernelGGL(rnn_fused, grid, block, 0, stream,
                       x, W, U, b, Wd, bd, out, B);
}

// Round 4
// 135.296 us; speedup vs baseline: 2.0886x; 2.0886x over previous
//
#include <hip/hip_runtime.h>

#define TT 200
#define FF 32
#define HH 50
#define MROWS 16     // batch rows per block
#define PITCH 68     // u32 pitch of h LDS rows (68%32=4 -> 2-way max on writes)

typedef __attribute__((ext_vector_type(8))) short short8;   // 8 bf16 = 4 VGPR
typedef __attribute__((ext_vector_type(4))) float f32x4;
typedef __attribute__((ext_vector_type(4))) unsigned int uint32x4;

__device__ __forceinline__ unsigned short f2bf_rne(float f) {
    unsigned u = __float_as_uint(f);
    unsigned r = u + 0x7fffu + ((u >> 16) & 1u);
    return (unsigned short)(r >> 16);
}
__device__ __forceinline__ float fast_tanh(float x) {
    float e = __expf(2.0f * x);
    return 1.0f - __fdividef(2.0f, e + 1.0f);
}
__device__ __forceinline__ float trunc_hi(float v) {   // bf16-truncate, as f32
    return __uint_as_float(__float_as_uint(v) & 0xffff0000u);
}
__device__ __forceinline__ f32x4 mfma16(short8 a, short8 b, f32x4 c) {
    return __builtin_amdgcn_mfma_f32_16x16x32_bf16(a, b, c, 0, 0, 0);
}

// Split a fp32 column-slice of M[kdim x 50] into bf16 hi/lo B-fragments.
// Fragment model (8-contiguous): lane(r,g) elem e -> B[k=kbase+8g+e][col=c].
__device__ __forceinline__ void build_bfrag(const float* __restrict__ M, int kbase,
                                            int kmax, int c, bool cv, int g,
                                            short8& hi, short8& lo) {
    unsigned ph[4], pl[4];
#pragma unroll
    for (int p = 0; p < 4; ++p) {
        const int k0 = kbase + 8 * g + 2 * p, k1 = k0 + 1;
        float v0 = (cv && k0 < kmax) ? M[k0 * HH + c] : 0.0f;
        float v1 = (cv && k1 < kmax) ? M[k1 * HH + c] : 0.0f;
        unsigned short h0 = f2bf_rne(v0), h1 = f2bf_rne(v1);
        ph[p] = ((unsigned)h1 << 16) | h0;
        float r0 = v0 - __uint_as_float((unsigned)h0 << 16);
        float r1 = v1 - __uint_as_float((unsigned)h1 << 16);
        unsigned short l0 = f2bf_rne(r0), l1 = f2bf_rne(r1);
        pl[p] = ((unsigned)l1 << 16) | l0;
    }
    uint32x4 h4 = {ph[0], ph[1], ph[2], ph[3]};
    uint32x4 l4 = {pl[0], pl[1], pl[2], pl[3]};
    hi = __builtin_bit_cast(short8, h4);
    lo = __builtin_bit_cast(short8, l4);
}

// Truncation-split 8 fp32 -> bf16 hi/lo frags. hi = top16 bits (exact residual
// recapture in lo makes trunc as good as RNE-split). 6 VALU per pair via v_perm.
__device__ __forceinline__ void split8(float4 a, float4 b, short8& hi, short8& lo) {
    float v[8] = {a.x, a.y, a.z, a.w, b.x, b.y, b.z, b.w};
    unsigned ph[4], pl[4];
#pragma unroll
    for (int p = 0; p < 4; ++p) {
        unsigned u0 = __float_as_uint(v[2 * p]);
        unsigned u1 = __float_as_uint(v[2 * p + 1]);
        ph[p] = __builtin_amdgcn_perm(u1, u0, 0x07060302u);  // (u1.hi16<<16)|u0.hi16
        float r0 = v[2 * p]     - __uint_as_float(u0 & 0xffff0000u);
        float r1 = v[2 * p + 1] - __uint_as_float(u1 & 0xffff0000u);
        pl[p] = __builtin_amdgcn_perm(__float_as_uint(r1), __float_as_uint(r0), 0x07060302u);
    }
    uint32x4 h4 = {ph[0], ph[1], ph[2], ph[3]};
    uint32x4 l4 = {pl[0], pl[1], pl[2], pl[3]};
    hi = __builtin_bit_cast(short8, h4);
    lo = __builtin_bit_cast(short8, l4);
}

// Block = 16 rows, 2 waves. Wave w owns N-tiles {2w, 2w+1} (cols 32w..32w+31).
// Per step: C[16,64] = bias + x_t@W + h@U via split-bf16 MFMA; tanh; h packed
// (lo16<<16|hi16) per elem into LDS [row][j]; next step reads A-frags from it.
// Double-buffered h -> one barrier per step.
__global__
__attribute__((amdgpu_flat_work_group_size(128, 128)))
__attribute__((amdgpu_waves_per_eu(1, 1)))
void rnn_mfma(const float* __restrict__ x, const float* __restrict__ W,
              const float* __restrict__ U, const float* __restrict__ b,
              const float* __restrict__ Wd, const float* __restrict__ bd,
              float* __restrict__ out)
{
    __shared__ unsigned int hbuf[2][MROWS][PITCH];
    __shared__ float headbuf[2][MROWS];

    const int tid = threadIdx.x;
    const int w = tid >> 6;      // wave id 0/1
    const int l = tid & 63;
    const int r = l & 15;        // fragment row/col lane index
    const int g = l >> 4;        // fragment k-group
    const int rb = blockIdx.x * MROWS;

    // ---- loop-invariant weight fragments (hi/lo split) ----
    const int c0 = 32 * w + r, c1 = c0 + 16;   // this wave's two output cols
    const bool cv0 = (c0 < HH), cv1 = (c1 < HH);
    short8 Whi0, Wlo0, Whi1, Wlo1;
    build_bfrag(W, 0, FF, c0, cv0, g, Whi0, Wlo0);
    build_bfrag(W, 0, FF, c1, cv1, g, Whi1, Wlo1);
    short8 Uhi00, Ulo00, Uhi01, Ulo01, Uhi10, Ulo10, Uhi11, Ulo11;
    build_bfrag(U, 0,  HH, c0, cv0, g, Uhi00, Ulo00);   // tile0, k 0..31
    build_bfrag(U, 32, HH, c0, cv0, g, Uhi01, Ulo01);   // tile0, k 32..63
    build_bfrag(U, 0,  HH, c1, cv1, g, Uhi10, Ulo10);
    build_bfrag(U, 32, HH, c1, cv1, g, Uhi11, Ulo11);
    const float bias0 = cv0 ? b[c0] : 0.0f;
    const float bias1 = cv1 ? b[c1] : 0.0f;
    const float wd0 = cv0 ? Wd[c0] : 0.0f;
    const float wd1 = cv1 ? Wd[c1] : 0.0f;

    // ---- x stream: lane holds x[rb+r][t][8g..8g+7], prefetch depth 2 ----
    const float* xrow = x + ((size_t)(rb + r) * TT) * FF + 8 * g;
    float4 x0a = *(const float4*)(xrow);
    float4 x0b = *(const float4*)(xrow + 4);
    float4 x1a = *(const float4*)(xrow + FF);
    float4 x1b = *(const float4*)(xrow + FF + 4);

    float hf0[4], hf1[4];   // final h values (C-layout), kept for the head

    auto step = [&](int t, float4& xa, float4& xb) {
        // split current x into A-frags, then reuse regs to prefetch t+2
        short8 xahi, xalo;
        split8(xa, xb, xahi, xalo);
        int tn = t + 2; if (tn > TT - 1) tn = TT - 1;
        xa = *(const float4*)(xrow + tn * FF);
        xb = *(const float4*)(xrow + tn * FF + 4);

        f32x4 acc0 = {bias0, bias0, bias0, bias0};
        f32x4 acc1 = {bias1, bias1, bias1, bias1};

        // x_t @ W  (3 split products x 2 tiles)
        acc0 = mfma16(xahi, Whi0, acc0);
        acc1 = mfma16(xahi, Whi1, acc1);
        acc0 = mfma16(xalo, Whi0, acc0);
        acc1 = mfma16(xalo, Whi1, acc1);
        acc0 = mfma16(xahi, Wlo0, acc0);
        acc1 = mfma16(xahi, Wlo1, acc1);

        if (t > 0) {
            // read h A-frags from LDS: elem e -> h[row=r][k=32ks+8g+e]
            const int buf = t & 1;
            short8 hh0, hl0, hh1, hl1;
            {
                const unsigned* base = &hbuf[buf][r][8 * g];
                uint32x4 p0 = *(const uint32x4*)(base);
                uint32x4 p1 = *(const uint32x4*)(base + 4);
                unsigned ph[4], pl[4];
                ph[0] = __builtin_amdgcn_perm(p0[1], p0[0], 0x05040100u);
                ph[1] = __builtin_amdgcn_perm(p0[3], p0[2], 0x05040100u);
                ph[2] = __builtin_amdgcn_perm(p1[1], p1[0], 0x05040100u);
                ph[3] = __builtin_amdgcn_perm(p1[3], p1[2], 0x05040100u);
                pl[0] = __builtin_amdgcn_perm(p0[1], p0[0], 0x07060302u);
                pl[1] = __builtin_amdgcn_perm(p0[3], p0[2], 0x07060302u);
                pl[2] = __builtin_amdgcn_perm(p1[3-2], p1[0], 0x07060302u); // p1[1],p1[0]
                pl[3] = __builtin_amdgcn_perm(p1[3], p1[2], 0x07060302u);
                uint32x4 h4 = {ph[0], ph[1], ph[2], ph[3]};
                uint32x4 l4 = {pl[0], pl[1], pl[2], pl[3]};
                hh0 = __builtin_bit_cast(short8, h4);
                hl0 = __builtin_bit_cast(short8, l4);
            }
            {
                const unsigned* base = &hbuf[buf][r][32 + 8 * g];
                uint32x4 p0 = *(const uint32x4*)(base);
                uint32x4 p1 = *(const uint32x4*)(base + 4);
                unsigned ph[4], pl[4];
                ph[0] = __builtin_amdgcn_perm(p0[1], p0[0], 0x05040100u);
                ph[1] = __builtin_amdgcn_perm(p0[3], p0[2], 0x05040100u);
                ph[2] = __builtin_amdgcn_perm(p1[1], p1[0], 0x05040100u);
                ph[3] = __builtin_amdgcn_perm(p1[3], p1[2], 0x05040100u);
                pl[0] = __builtin_amdgcn_perm(p0[1], p0[0], 0x07060302u);
                pl[1] = __builtin_amdgcn_perm(p0[3], p0[2], 0x07060302u);
                pl[2] = __builtin_amdgcn_perm(p1[1], p1[0], 0x07060302u);
                pl[3] = __builtin_amdgcn_perm(p1[3], p1[2], 0x07060302u);
                uint32x4 h4 = {ph[0], ph[1], ph[2], ph[3]};
                uint32x4 l4 = {pl[0], pl[1], pl[2], pl[3]};
                hh1 = __builtin_bit_cast(short8, h4);
                hl1 = __builtin_bit_cast(short8, l4);
            }
            // h @ U  (3 split products x 2 K-steps x 2 tiles)
            acc0 = mfma16(hh0, Uhi00, acc0);
            acc1 = mfma16(hh0, Uhi10, acc1);
            acc0 = mfma16(hl0, Uhi00, acc0);
            acc1 = mfma16(hl0, Uhi10, acc1);
            acc0 = mfma16(hh0, Ulo00, acc0);
            acc1 = mfma16(hh0, Ulo10, acc1);
            acc0 = mfma16(hh1, Uhi01, acc0);
            acc1 = mfma16(hh1, Uhi11, acc1);
            acc0 = mfma16(hl1, Uhi01, acc0);
            acc1 = mfma16(hl1, Uhi11, acc1);
            acc0 = mfma16(hh1, Ulo01, acc0);
            acc1 = mfma16(hh1, Ulo11, acc1);
        }

        // tanh + pack (lo16<<16|hi16) + publish h_{t+1}
        const int nbuf = (t + 1) & 1;
        unsigned* wptr = &hbuf[nbuf][4 * g][32 * w + r];   // row 4g+i = +i*PITCH
#pragma unroll
        for (int i = 0; i < 4; ++i) {
            float h0 = fast_tanh(acc0[i]);
            float h1 = fast_tanh(acc1[i]);
            hf0[i] = h0; hf1[i] = h1;
            float r0 = h0 - trunc_hi(h0);
            float r1 = h1 - trunc_hi(h1);
            wptr[i * PITCH]      = __builtin_amdgcn_perm(__float_as_uint(r0), __float_as_uint(h0), 0x07060302u);
            wptr[i * PITCH + 16] = __builtin_amdgcn_perm(__float_as_uint(r1), __float_as_uint(h1), 0x07060302u);
        }
        __syncthreads();
    };

    for (int t = 0; t < TT; t += 2) {
        step(t,     x0a, x0b);
        step(t + 1, x1a, x1b);
    }

    // ---- head: out[row] = relu(sum_j h[row][j]*Wd[j] + bd) ----
    float pp[4];
#pragma unroll
    for (int i = 0; i < 4; ++i) {
        float p = hf0[i] * wd0 + hf1[i] * wd1;
        p += __shfl_xor(p, 1);
        p += __shfl_xor(p, 2);
        p += __shfl_xor(p, 4);
        p += __shfl_xor(p, 8);
        pp[i] = p;   // lanes with r==0 hold row-sum for row 4g+i (this wave's cols)
    }
    if (r == 0) {
#pragma unroll
        for (int i = 0; i < 4; ++i) headbuf[w][4 * g + i] = pp[i];
    }
    __syncthreads();
    if (w == 0 && l < MROWS)
        out[rb + l] = fmaxf(headbuf[0][l] + headbuf[1][l] + bd[0], 0.0f);
}

extern "C" void kernel_launch(void* const* d_in, const int* in_sizes, int n_in,
                              void* d_out, int out_size, void* d_ws, size_t ws_size,
                              hipStream_t stream) {
    const float* x  = (const float*)d_in[0];
    const float* W  = (const float*)d_in[1];
    const float* U  = (const float*)d_in[2];
    const float* b  = (const float*)d_in[3];
    const float* Wd = (const float*)d_in[4];
    const float* bd = (const float*)d_in[5];
    float* out = (float*)d_out;
    const int B = out_size;                       // 4096
    dim3 grid(B / MROWS), block(128);             // 256 blocks, 2 waves each
    hipLaunchKernelGGL(rnn_mfma, grid, block, 0, stream,
                       x, W, U, b, Wd, bd, out);
    (void)d_ws; (void)ws_size; (void)in_sizes; (void)n_in;
}